// Round 2
// baseline (447.888 us; speedup 1.0000x reference)
//
#include <hip/hip_runtime.h>

#define B_    32
#define S_    577
#define HID_  768
#define NH_   12
#define HD_   64
#define SPAD  640
#define SB_   5            // s-blocks of 128 per batch (5*128 = 640)
#define MT_   160          // b-aligned m-tiles: 32 * 5
#define KT_   12           // 768/64
#define NT_   18           // 2304/128

typedef __attribute__((ext_vector_type(8))) short short8;
typedef __attribute__((ext_vector_type(4))) short short4s;
typedef __attribute__((ext_vector_type(4))) float float4_;

#define WAITV(n) asm volatile("s_waitcnt vmcnt(" #n ")" ::: "memory")

static __device__ __forceinline__ float bf2f(short s) {
    union { float f; unsigned u; } cvt;
    cvt.u = ((unsigned)(unsigned short)s) << 16;
    return cvt.f;
}
static __device__ __forceinline__ short f2bf(float f) {
    union { float f; unsigned u; } cvt;
    cvt.f = f;
    unsigned u = cvt.u;
    unsigned r = u + 0x7FFF + ((u >> 16) & 1);   // RNE; finite inputs
    return (short)(r >> 16);
}
// async global->LDS: per-lane 16B from g(lane), written to ldsbase + lane*16
static __device__ __forceinline__ void gl_lds16(const short* g, short* l) {
    __builtin_amdgcn_global_load_lds(
        (const __attribute__((address_space(1))) unsigned int*)g,
        (__attribute__((address_space(3))) unsigned int*)l,
        16, 0, 0);
}

// ---------------------------------------------------------------------------
// A image: ximg[mt=b*5+sb][kt][kg8][row128][8]  (byte-exact LDS staging image)
// ---------------------------------------------------------------------------
__global__ __launch_bounds__(256) void convA_kernel(
    const float* __restrict__ X, short* __restrict__ ximg)
{
    const int mt = blockIdx.x, kt = blockIdx.y;
    const int b = mt / SB_, sb = mt - b * SB_;
    short* img = ximg + ((size_t)mt * KT_ + kt) * 8192;
#pragma unroll
    for (int i = 0; i < 4; ++i) {
        const int j = i * 256 + threadIdx.x;   // 0..1023
        const int row = j >> 3, kg = j & 7;
        const int s = sb * 128 + row;
        const int srow = (s < S_) ? s : 0;     // pad rows: any finite
        const float* src = X + ((size_t)b * S_ + srow) * HID_ + kt * 64 + kg * 8;
        float4_ f0 = *(const float4_*)src;
        float4_ f1 = *(const float4_*)(src + 4);
        short8 s8;
#pragma unroll
        for (int e = 0; e < 4; ++e) { s8[e] = f2bf(f0[e]); s8[e + 4] = f2bf(f1[e]); }
        *(short8*)(img + ((size_t)kg * 128 + row) * 8) = s8;
    }
}

// B image: wimg[nt18][kt][kg8][row128][8], nt = z*6 + local (row = n in tile)
__global__ __launch_bounds__(256) void convB_kernel(
    const float* __restrict__ Wq, const float* __restrict__ Wk,
    const float* __restrict__ Wv, short* __restrict__ wimg)
{
    const int nt = blockIdx.x, kt = blockIdx.y;
    const int z = nt / 6;
    const float* W = (z == 0) ? Wq : (z == 1) ? Wk : Wv;
    const int n0 = (nt - z * 6) * 128;
    short* img = wimg + ((size_t)nt * KT_ + kt) * 8192;
#pragma unroll
    for (int i = 0; i < 4; ++i) {
        const int j = i * 256 + threadIdx.x;
        const int row = j >> 3, kg = j & 7;
        const float* src = W + (size_t)(n0 + row) * HID_ + kt * 64 + kg * 8;
        float4_ f0 = *(const float4_*)src;
        float4_ f1 = *(const float4_*)(src + 4);
        short8 s8;
#pragma unroll
        for (int e = 0; e < 4; ++e) { s8[e] = f2bf(f0[e]); s8[e + 4] = f2bf(f1[e]); }
        *(short8*)(img + ((size_t)kg * 128 + row) * 8) = s8;
    }
}

// ---------------------------------------------------------------------------
// Fused QKV GEMM, counted-vmcnt half-K phase pipeline (T3+T4+T5), XCD swizzle.
// 24 phases (2 per K-step); stage unit = 16KB half-K (4 gl_lds16/thread);
// 3 units in flight -> s_waitcnt vmcnt(12), never 0 in steady state.
// grid = 2880 flat, block 256 (4 waves, 2x2 of 64x64).
// ---------------------------------------------------------------------------
__global__ __launch_bounds__(256) void gemm_kernel(
    const short* __restrict__ ximg, const short* __restrict__ wimg,
    const float* __restrict__ bq, const float* __restrict__ bk,
    const float* __restrict__ bv,
    const float* __restrict__ lat, const int* __restrict__ mixw,
    short* __restrict__ qo, short* __restrict__ ko, short* __restrict__ vo)
{
    // A0 [0,8192) A1 [8192,16384) B0 [16384,24576) B1 [24576,32768)  (shorts)
    __shared__ __align__(16) short lds[32768];

    // XCD-aware swizzle: each XCD gets a contiguous mt-major chunk.
    const int bid0 = blockIdx.x;                     // 0..2879
    const int bids = (bid0 & 7) * 360 + (bid0 >> 3); // bijective (2880%8==0)
    const int mt = bids / NT_;
    const int nt = bids - mt * NT_;

    const int z   = nt / 6;
    const int nz0 = (nt - z * 6) * 128;
    const int b   = mt / SB_;
    const int s0  = (mt - b * SB_) * 128;

    const int tid  = threadIdx.x;
    const int wave = tid >> 6;
    const int lane = tid & 63;
    const int quad = lane >> 4;
    const int l16  = lane & 15;

    const short* ag = ximg + ((size_t)mt * KT_) * 8192;
    const short* bg = wimg + ((size_t)nt * KT_) * 8192;

    float4_ acc[4][4] = {};
    const int r0 = (wave & 1) * 64 + l16;
    const int c0 = (wave >> 1) * 64 + l16;

    // stage unit P (= kt*2 + h): half-K slab of A and B -> 4 gl_lds16/thread
    auto STAGE = [&](int P) {
        const int kt = P >> 1, h = P & 1;
        const size_t off = (size_t)kt * 8192 + h * 4096;
        const short* as = ag + off;
        const short* bs = bg + off;
        short* Ad = lds + ((kt & 1) * 8192 + h * 4096);
        short* Bd = lds + 16384 + ((kt & 1) * 8192 + h * 4096);
#pragma unroll
        for (int i = 0; i < 2; ++i) {
            gl_lds16(as + (i * 256 + tid) * 8, Ad + (i * 256 + wave * 64) * 8);
            gl_lds16(bs + (i * 256 + tid) * 8, Bd + (i * 256 + wave * 64) * 8);
        }
    };

    STAGE(0); STAGE(1); STAGE(2);          // 12 loads in flight

    for (int P = 0; P < 2 * KT_; ++P) {
        if (P < 2 * KT_ - 3) STAGE(P + 3);
        if (P < 2 * KT_ - 3)      { WAITV(12); }
        else if (P == 2 * KT_ - 3){ WAITV(8);  }
        else if (P == 2 * KT_ - 2){ WAITV(4);  }
        else                      { WAITV(0);  }
        __builtin_amdgcn_sched_barrier(0);
        __builtin_amdgcn_s_barrier();
        __builtin_amdgcn_sched_barrier(0);

        const short* Ab = lds + ((P >> 1) & 1) * 8192;
        const short* Bb = lds + 16384 + ((P >> 1) & 1) * 8192;
        const int kb = ((P & 1) * 4 + quad) * 128;
        short8 af[4], bf4[4];
#pragma unroll
        for (int mi = 0; mi < 4; ++mi)
            af[mi] = *(const short8*)(Ab + (kb + r0 + mi * 16) * 8);
#pragma unroll
        for (int g = 0; g < 4; ++g)
            bf4[g] = *(const short8*)(Bb + (kb + c0 + g * 16) * 8);
        __builtin_amdgcn_s_setprio(1);
#pragma unroll
        for (int mi = 0; mi < 4; ++mi)
#pragma unroll
            for (int g = 0; g < 4; ++g)
                acc[mi][g] = __builtin_amdgcn_mfma_f32_16x16x32_bf16(
                    af[mi], bf4[g], acc[mi][g], 0, 0, 0);
        __builtin_amdgcn_s_setprio(0);
        __builtin_amdgcn_sched_barrier(0);
        __builtin_amdgcn_s_barrier();       // last reader done before re-stage
    }

    // ---------------- epilogue via LDS, coalesced 16B stores ----------------
    const int mwv = *mixw;
    const float* bb = (z == 0) ? bq : (z == 1) ? bk : bv;
    const int hh   = (nz0 + (wave >> 1) * 64) >> 6;       // head 0..11
    const size_t bh = (size_t)b * NH_ + hh;
    const int sW   = s0 + (wave & 1) * 64;                // 64-aligned
    const int ch   = sW >> 6;                             // image chunk 0..9
    short* P = lds + wave * 4608;                         // 64*72 shorts

    if (z < 2) {
        // row-major: P[s_local][d]
#pragma unroll
        for (int mi = 0; mi < 4; ++mi)
#pragma unroll
            for (int i = 0; i < 4; ++i) {
                const int ml = mi * 16 + quad * 4 + i;
                const int s  = sW + ml;
                const float* lp =
                    lat + (bh * S_ + (s < S_ ? s : S_ - 1)) * HD_;
#pragma unroll
                for (int g = 0; g < 4; ++g) {
                    const int d = g * 16 + l16;
                    float val = acc[mi][g][i] + bb[hh * 64 + d];
                    if (z == mwv) val *= lp[d];
                    P[ml * 72 + d] = f2bf(val);
                }
            }
    } else {
        // transposed: P[d][s_local] (b64 writes of 4 consecutive s)
#pragma unroll
        for (int mi = 0; mi < 4; ++mi)
#pragma unroll
            for (int g = 0; g < 4; ++g) {
                const int d  = g * 16 + l16;
                const int mb = mi * 16 + quad * 4;
                short4s w;
#pragma unroll
                for (int i = 0; i < 4; ++i) {
                    const int s = sW + mb + i;
                    float val = acc[mi][g][i] + bb[hh * 64 + d];
                    if (mwv == 2)
                        val *= lat[(bh * S_ + (s < S_ ? s : S_ - 1)) * HD_ + d];
                    w[i] = f2bf(val);
                }
                *(short4s*)(P + d * 72 + mb) = w;
            }
    }
    __syncthreads();

    const int rr = lane >> 3, cc = lane & 7;
    if (z == 0) {
        short* qb = qo + (size_t)bh * SPAD * HD_;
#pragma unroll
        for (int j = 0; j < 8; ++j) {
            const int r = j * 8 + rr;                     // s_local
            *(short8*)(qb + (size_t)(sW + r) * 64 + cc * 8) =
                *(const short8*)(P + r * 72 + cc * 8);
        }
    } else if (z == 1) {
        short* kb = ko + ((size_t)bh * 10 + ch) * 4096;
#pragma unroll
        for (int j = 0; j < 8; ++j) {
            const int r = j * 8 + rr;                     // s_local
            *(short8*)(kb + (cc * 64 + r) * 8) =
                *(const short8*)(P + r * 72 + cc * 8);
        }
    } else {
        short* vb = vo + ((size_t)bh * 10 + ch) * 4096;
#pragma unroll
        for (int j = 0; j < 8; ++j) {
            const int r = j * 8 + rr;                     // d
            *(short8*)(vb + (cc * 64 + r) * 8) =
                *(const short8*)(P + r * 72 + cc * 8);
        }
    }
}

// ---------------------------------------------------------------------------
// Flash attention, counted-vmcnt double-buffered K/V staging.
// grid = (384 bh, 10 qtiles of 64), block 256 (4 waves x 16 q-rows).
// ---------------------------------------------------------------------------
__global__ __launch_bounds__(256) void attn_kernel(
    const short* __restrict__ q, const short* __restrict__ k,
    const short* __restrict__ vt, float* __restrict__ out)
{
    __shared__ __align__(16) short Kt[2][4096];       // [kg8][key64][8] x2
    __shared__ __align__(16) short Vt[2][4096];       // [kg8][d64][8]   x2
    __shared__ __align__(16) short pbuf[4][16][64];   // per-wave P

    const int bh   = blockIdx.x;
    const int b    = bh / NH_;
    const int h    = bh - b * NH_;
    const int tid  = threadIdx.x;
    const int wave = tid >> 6;
    const int lane = tid & 63;
    const int quad = lane >> 4;
    const int l16  = lane & 15;
    const int q0   = blockIdx.y * 64 + wave * 16;

    const short* qp   = q  + (size_t)bh * SPAD * HD_;
    const short* kimg = k  + (size_t)bh * 40960;
    const short* vimg = vt + (size_t)bh * 40960;

    const short8 aq0 = *(const short8*)(qp + (size_t)(q0 + l16) * HD_ + quad * 8);
    const short8 aq1 = *(const short8*)(qp + (size_t)(q0 + l16) * HD_ + 32 + quad * 8);

    auto STAGE = [&](int kc) {
#pragma unroll
        for (int i = 0; i < 2; ++i) {
            gl_lds16(kimg + (size_t)kc * 4096 + (i * 256 + tid) * 8,
                     Kt[kc & 1] + (i * 256 + wave * 64) * 8);
            gl_lds16(vimg + (size_t)kc * 4096 + (i * 256 + tid) * 8,
                     Vt[kc & 1] + (i * 256 + wave * 64) * 8);
        }
    };

    float m_i[4], l_i[4];
    float4_ O[4] = {};
#pragma unroll
    for (int i = 0; i < 4; ++i) { m_i[i] = -3.0e38f; l_i[i] = 0.0f; }

    STAGE(0);

    for (int kc = 0; kc < 10; ++kc) {
        const int key0 = kc * 64;
        if (kc < 9) STAGE(kc + 1);
        if (kc < 9) { WAITV(4); } else { WAITV(0); }
        __builtin_amdgcn_sched_barrier(0);
        __builtin_amdgcn_s_barrier();
        __builtin_amdgcn_sched_barrier(0);

        const short* Kb = Kt[kc & 1];
        const short* Vb = Vt[kc & 1];

        float4_ sc[4] = {};
        __builtin_amdgcn_s_setprio(1);
#pragma unroll
        for (int c = 0; c < 2; ++c) {
            const int kb = (c * 4 + quad) * 64;
            const short8 aq = c ? aq1 : aq0;
#pragma unroll
            for (int g = 0; g < 4; ++g) {
                short8 bk8 = *(const short8*)(Kb + (kb + g * 16 + l16) * 8);
                sc[g] = __builtin_amdgcn_mfma_f32_16x16x32_bf16(aq, bk8, sc[g], 0, 0, 0);
            }
        }
        __builtin_amdgcn_s_setprio(0);

        float kmask[4];
#pragma unroll
        for (int g = 0; g < 4; ++g)
            kmask[g] = (key0 + g * 16 + l16 < S_) ? 0.0f : -3.0e38f;

        float alpha[4];
#pragma unroll
        for (int i = 0; i < 4; ++i) {
            float s0 = sc[0][i] * 0.125f + kmask[0];
            float s1 = sc[1][i] * 0.125f + kmask[1];
            float s2 = sc[2][i] * 0.125f + kmask[2];
            float s3 = sc[3][i] * 0.125f + kmask[3];
            float cm = fmaxf(fmaxf(s0, s1), fmaxf(s2, s3));
#pragma unroll
            for (int off = 1; off < 16; off <<= 1)
                cm = fmaxf(cm, __shfl_xor(cm, off));
            const float mn = fmaxf(m_i[i], cm);
            alpha[i] = __expf(m_i[i] - mn);
            m_i[i] = mn;
            const short p0 = f2bf(__expf(s0 - mn));
            const short p1 = f2bf(__expf(s1 - mn));
            const short p2 = f2bf(__expf(s2 - mn));
            const short p3 = f2bf(__expf(s3 - mn));
            pbuf[wave][quad * 4 + i][l16]      = p0;
            pbuf[wave][quad * 4 + i][l16 + 16] = p1;
            pbuf[wave][quad * 4 + i][l16 + 32] = p2;
            pbuf[wave][quad * 4 + i][l16 + 48] = p3;
            float rs = (bf2f(p0) + bf2f(p1)) + (bf2f(p2) + bf2f(p3));
#pragma unroll
            for (int off = 1; off < 16; off <<= 1)
                rs += __shfl_xor(rs, off);
            l_i[i] = l_i[i] * alpha[i] + rs;
        }

#pragma unroll
        for (int g = 0; g < 4; ++g)
#pragma unroll
            for (int i = 0; i < 4; ++i) O[g][i] *= alpha[i];

        __builtin_amdgcn_s_setprio(1);
#pragma unroll
        for (int c = 0; c < 2; ++c) {
            const short8 ap = *(const short8*)(&pbuf[wave][l16][c * 32 + quad * 8]);
            const int kb = (c * 4 + quad) * 64;
#pragma unroll
            for (int g = 0; g < 4; ++g) {
                short8 bv8 = *(const short8*)(Vb + (kb + g * 16 + l16) * 8);
                O[g] = __builtin_amdgcn_mfma_f32_16x16x32_bf16(ap, bv8, O[g], 0, 0, 0);
            }
        }
        __builtin_amdgcn_s_setprio(0);
        __builtin_amdgcn_sched_barrier(0);
        __builtin_amdgcn_s_barrier();       // last reader done before re-stage
    }

#pragma unroll
    for (int i = 0; i < 4; ++i) {
        const int s = q0 + quad * 4 + i;
        if (s >= S_) continue;
        const float inv = 1.0f / l_i[i];
#pragma unroll
        for (int g = 0; g < 4; ++g)
            out[((size_t)b * S_ + s) * HID_ + h * HD_ + g * 16 + l16] = O[g][i] * inv;
    }
}

extern "C" void kernel_launch(void* const* d_in, const int* in_sizes, int n_in,
                              void* d_out, int out_size, void* d_ws, size_t ws_size,
                              hipStream_t stream) {
    (void)in_sizes; (void)n_in; (void)out_size; (void)ws_size;

    const float* X   = (const float*)d_in[0];
    const float* lat = (const float*)d_in[1];
    const float* Wq  = (const float*)d_in[2];
    const float* bq  = (const float*)d_in[3];
    const float* Wk  = (const float*)d_in[4];
    const float* bk  = (const float*)d_in[5];
    const float* Wv  = (const float*)d_in[6];
    const float* bv  = (const float*)d_in[7];
    const int* mixw  = (const int*)d_in[8];
    float* out = (float*)d_out;

    const size_t per = (size_t)B_ * NH_ * SPAD * HD_;   // 15,728,640
    short* qw   = (short*)d_ws;
    short* kw   = qw + per;
    short* vw   = kw + per;
    short* wimg = vw + per;                             // 18*12*8192 = 1,769,472
    short* ximg = wimg + (size_t)NT_ * KT_ * 8192;      // 160*12*8192 = 15,728,640

    convA_kernel<<<dim3(MT_, KT_), 256, 0, stream>>>(X, ximg);
    convB_kernel<<<dim3(NT_, KT_), 256, 0, stream>>>(Wq, Wk, Wv, wimg);
    gemm_kernel<<<dim3(NT_ * MT_), 256, 0, stream>>>(
        ximg, wimg, bq, bk, bv, lat, mixw, qw, kw, vw);
    attn_kernel<<<dim3(384, 10), 256, 0, stream>>>(qw, kw, vw, out);
}

// Round 3
// 406.538 us; speedup vs baseline: 1.1017x; 1.1017x over previous
//
#include <hip/hip_runtime.h>

#define B_    32
#define S_    577
#define HID_  768
#define NH_   12
#define HD_   64
#define SPAD  640
#define SB_   5            // s-blocks of 128 per batch (5*128 = 640)
#define MT_   160          // b-aligned m-tiles: 32 * 5
#define KT_   12           // 768/64
#define NT_   18           // 2304/128

typedef __attribute__((ext_vector_type(8))) short short8;
typedef __attribute__((ext_vector_type(4))) short short4s;
typedef __attribute__((ext_vector_type(4))) float float4_;

static __device__ __forceinline__ float bf2f(short s) {
    union { float f; unsigned u; } cvt;
    cvt.u = ((unsigned)(unsigned short)s) << 16;
    return cvt.f;
}
static __device__ __forceinline__ short f2bf(float f) {
    union { float f; unsigned u; } cvt;
    cvt.f = f;
    unsigned u = cvt.u;
    unsigned r = u + 0x7FFF + ((u >> 16) & 1);   // RNE; finite inputs
    return (short)(r >> 16);
}

// ---------------------------------------------------------------------------
// A image: ximg[mt=b*5+sb][kt][kg8][row128][8]  (MFMA-fragment-ordered bf16)
// ---------------------------------------------------------------------------
__global__ __launch_bounds__(256) void convA_kernel(
    const float* __restrict__ X, short* __restrict__ ximg)
{
    const int mt = blockIdx.x, kt = blockIdx.y;
    const int b = mt / SB_, sb = mt - b * SB_;
    short* img = ximg + ((size_t)mt * KT_ + kt) * 8192;
#pragma unroll
    for (int i = 0; i < 4; ++i) {
        const int j = i * 256 + threadIdx.x;   // 0..1023
        const int row = j >> 3, kg = j & 7;
        const int s = sb * 128 + row;
        const int srow = (s < S_) ? s : 0;     // pad rows: any finite
        const float* src = X + ((size_t)b * S_ + srow) * HID_ + kt * 64 + kg * 8;
        float4_ f0 = *(const float4_*)src;
        float4_ f1 = *(const float4_*)(src + 4);
        short8 s8;
#pragma unroll
        for (int e = 0; e < 4; ++e) { s8[e] = f2bf(f0[e]); s8[e + 4] = f2bf(f1[e]); }
        *(short8*)(img + ((size_t)kg * 128 + row) * 8) = s8;
    }
}

// B image: wimg[nt18][kt][kg8][row128][8], nt = z*6 + local (row = n in tile)
__global__ __launch_bounds__(256) void convB_kernel(
    const float* __restrict__ Wq, const float* __restrict__ Wk,
    const float* __restrict__ Wv, short* __restrict__ wimg)
{
    const int nt = blockIdx.x, kt = blockIdx.y;
    const int z = nt / 6;
    const float* W = (z == 0) ? Wq : (z == 1) ? Wk : Wv;
    const int n0 = (nt - z * 6) * 128;
    short* img = wimg + ((size_t)nt * KT_ + kt) * 8192;
#pragma unroll
    for (int i = 0; i < 4; ++i) {
        const int j = i * 256 + threadIdx.x;
        const int row = j >> 3, kg = j & 7;
        const float* src = W + (size_t)(n0 + row) * HID_ + kt * 64 + kg * 8;
        float4_ f0 = *(const float4_*)src;
        float4_ f1 = *(const float4_*)(src + 4);
        short8 s8;
#pragma unroll
        for (int e = 0; e < 4; ++e) { s8[e] = f2bf(f0[e]); s8[e + 4] = f2bf(f1[e]); }
        *(short8*)(img + ((size_t)kg * 128 + row) * 8) = s8;
    }
}

// ---------------------------------------------------------------------------
// Fused QKV GEMM, register-direct fragment streaming. The images are already
// in fragment order, so each A/B fragment is a coalesced global short8 load
// (4 x 256B segments per wave). NO staging LDS, NO barriers anywhere; LDS is
// only the per-wave epilogue transpose scratch (36 KB -> 4 blocks/CU cap).
// grid = 2880 flat (XCD-swizzled, mt-major per XCD), block 256 (4 waves).
// ---------------------------------------------------------------------------
__global__ __launch_bounds__(256) void gemm_kernel(
    const short* __restrict__ ximg, const short* __restrict__ wimg,
    const float* __restrict__ bq, const float* __restrict__ bk,
    const float* __restrict__ bv,
    const float* __restrict__ lat, const int* __restrict__ mixw,
    short* __restrict__ qo, short* __restrict__ ko, short* __restrict__ vo)
{
    __shared__ __align__(16) short eP[4][4608];   // per-wave 64x72, 36 KB

    // XCD-aware swizzle: each XCD gets a contiguous mt-major chunk.
    const int bid0 = blockIdx.x;                     // 0..2879
    const int bids = (bid0 & 7) * 360 + (bid0 >> 3); // bijective (2880%8==0)
    const int mt = bids / NT_;
    const int nt = bids - mt * NT_;

    const int z   = nt / 6;
    const int nz0 = (nt - z * 6) * 128;
    const int b   = mt / SB_;
    const int s0  = (mt - b * SB_) * 128;

    const int tid  = threadIdx.x;
    const int wave = tid >> 6;
    const int lane = tid & 63;
    const int quad = lane >> 4;
    const int l16  = lane & 15;

    const short* ag = ximg + ((size_t)mt * KT_) * 8192;
    const short* bg = wimg + ((size_t)nt * KT_) * 8192;

    float4_ acc[4][4] = {};
    const int r0 = (wave & 1) * 64 + l16;
    const int c0 = (wave >> 1) * 64 + l16;

    for (int kt = 0; kt < KT_; ++kt) {
        const short* ak = ag + (size_t)kt * 8192;
        const short* bk8p = bg + (size_t)kt * 8192;
#pragma unroll
        for (int c = 0; c < 2; ++c) {
            const int kb = (c * 4 + quad) * 128;
            short8 af[4], bf4[4];
#pragma unroll
            for (int mi = 0; mi < 4; ++mi)
                af[mi] = *(const short8*)(ak + (kb + r0 + mi * 16) * 8);
#pragma unroll
            for (int g = 0; g < 4; ++g)
                bf4[g] = *(const short8*)(bk8p + (kb + c0 + g * 16) * 8);
            __builtin_amdgcn_s_setprio(1);
#pragma unroll
            for (int mi = 0; mi < 4; ++mi)
#pragma unroll
                for (int g = 0; g < 4; ++g)
                    acc[mi][g] = __builtin_amdgcn_mfma_f32_16x16x32_bf16(
                        af[mi], bf4[g], acc[mi][g], 0, 0, 0);
            __builtin_amdgcn_s_setprio(0);
        }
    }

    // -------- epilogue via per-wave LDS scratch, coalesced 16B stores -------
    const int mwv = *mixw;
    const float* bb = (z == 0) ? bq : (z == 1) ? bk : bv;
    const int hh   = (nz0 + (wave >> 1) * 64) >> 6;       // head 0..11
    const size_t bh = (size_t)b * NH_ + hh;
    const int sW   = s0 + (wave & 1) * 64;                // 64-aligned
    const int ch   = sW >> 6;                             // image chunk 0..9
    short* P = eP[wave];

    if (z < 2) {
        // row-major: P[s_local][d]
#pragma unroll
        for (int mi = 0; mi < 4; ++mi)
#pragma unroll
            for (int i = 0; i < 4; ++i) {
                const int ml = mi * 16 + quad * 4 + i;
                const int s  = sW + ml;
                const float* lp =
                    lat + (bh * S_ + (s < S_ ? s : S_ - 1)) * HD_;
#pragma unroll
                for (int g = 0; g < 4; ++g) {
                    const int d = g * 16 + l16;
                    float val = acc[mi][g][i] + bb[hh * 64 + d];
                    if (z == mwv) val *= lp[d];
                    P[ml * 72 + d] = f2bf(val);
                }
            }
    } else {
        // transposed: P[d][s_local] (b64 writes of 4 consecutive s)
#pragma unroll
        for (int mi = 0; mi < 4; ++mi)
#pragma unroll
            for (int g = 0; g < 4; ++g) {
                const int d  = g * 16 + l16;
                const int mb = mi * 16 + quad * 4;
                short4s w;
#pragma unroll
                for (int i = 0; i < 4; ++i) {
                    const int s = sW + mb + i;
                    float val = acc[mi][g][i] + bb[hh * 64 + d];
                    if (mwv == 2)
                        val *= lat[(bh * S_ + (s < S_ ? s : S_ - 1)) * HD_ + d];
                    w[i] = f2bf(val);
                }
                *(short4s*)(P + d * 72 + mb) = w;
            }
    }
    // NO __syncthreads: scratch is strictly per-wave (write+read same wave).

    const int rr = lane >> 3, cc = lane & 7;
    if (z == 0) {
        short* qb = qo + (size_t)bh * SPAD * HD_;
#pragma unroll
        for (int j = 0; j < 8; ++j) {
            const int r = j * 8 + rr;                     // s_local
            *(short8*)(qb + (size_t)(sW + r) * 64 + cc * 8) =
                *(const short8*)(P + r * 72 + cc * 8);
        }
    } else if (z == 1) {
        short* kb = ko + ((size_t)bh * 10 + ch) * 4096;
#pragma unroll
        for (int j = 0; j < 8; ++j) {
            const int r = j * 8 + rr;                     // s_local
            *(short8*)(kb + (cc * 64 + r) * 8) =
                *(const short8*)(P + r * 72 + cc * 8);
        }
    } else {
        short* vb = vo + ((size_t)bh * 10 + ch) * 4096;
#pragma unroll
        for (int j = 0; j < 8; ++j) {
            const int r = j * 8 + rr;                     // d
            *(short8*)(vb + (cc * 64 + r) * 8) =
                *(const short8*)(P + r * 72 + cc * 8);
        }
    }
}

// ---------------------------------------------------------------------------
// Flash attention, register-direct K/V fragment streaming from the chunk
// images (L2/L3-resident). No K/V LDS staging, zero barriers; LDS is only the
// per-wave P buffer (8 KB). grid = 3840 flat, bh-major per XCD.
// ---------------------------------------------------------------------------
__global__ __launch_bounds__(256) void attn_kernel(
    const short* __restrict__ q, const short* __restrict__ k,
    const short* __restrict__ vt, float* __restrict__ out)
{
    __shared__ __align__(16) short pbuf[4][16][64];   // per-wave P, 8 KB

    const int bid0 = blockIdx.x;                      // 0..3839
    const int bids = (bid0 & 7) * 480 + (bid0 >> 3);  // bijective (3840%8==0)
    const int bh = bids / 10;
    const int qt = bids - bh * 10;

    const int b    = bh / NH_;
    const int h    = bh - b * NH_;
    const int tid  = threadIdx.x;
    const int wave = tid >> 6;
    const int lane = tid & 63;
    const int quad = lane >> 4;
    const int l16  = lane & 15;
    const int q0   = qt * 64 + wave * 16;

    const short* qp   = q  + (size_t)bh * SPAD * HD_;
    const short* kimg = k  + (size_t)bh * 40960;
    const short* vimg = vt + (size_t)bh * 40960;

    const short8 aq0 = *(const short8*)(qp + (size_t)(q0 + l16) * HD_ + quad * 8);
    const short8 aq1 = *(const short8*)(qp + (size_t)(q0 + l16) * HD_ + 32 + quad * 8);

    float m_i[4], l_i[4];
    float4_ O[4] = {};
#pragma unroll
    for (int i = 0; i < 4; ++i) { m_i[i] = -3.0e38f; l_i[i] = 0.0f; }

    for (int kc = 0; kc < 10; ++kc) {
        const int key0 = kc * 64;
        const short* Kc = kimg + (size_t)kc * 4096;
        const short* Vc = vimg + (size_t)kc * 4096;

        float4_ sc[4] = {};
#pragma unroll
        for (int c = 0; c < 2; ++c) {
            const int kb = (c * 4 + quad) * 64;
            const short8 aq = c ? aq1 : aq0;
            short8 bk8[4];
#pragma unroll
            for (int g = 0; g < 4; ++g)
                bk8[g] = *(const short8*)(Kc + (kb + g * 16 + l16) * 8);
            __builtin_amdgcn_s_setprio(1);
#pragma unroll
            for (int g = 0; g < 4; ++g)
                sc[g] = __builtin_amdgcn_mfma_f32_16x16x32_bf16(aq, bk8[g], sc[g], 0, 0, 0);
            __builtin_amdgcn_s_setprio(0);
        }

        float kmask[4];
#pragma unroll
        for (int g = 0; g < 4; ++g)
            kmask[g] = (key0 + g * 16 + l16 < S_) ? 0.0f : -3.0e38f;

        float alpha[4];
#pragma unroll
        for (int i = 0; i < 4; ++i) {
            float s0 = sc[0][i] * 0.125f + kmask[0];
            float s1 = sc[1][i] * 0.125f + kmask[1];
            float s2 = sc[2][i] * 0.125f + kmask[2];
            float s3 = sc[3][i] * 0.125f + kmask[3];
            float cm = fmaxf(fmaxf(s0, s1), fmaxf(s2, s3));
#pragma unroll
            for (int off = 1; off < 16; off <<= 1)
                cm = fmaxf(cm, __shfl_xor(cm, off));
            const float mn = fmaxf(m_i[i], cm);
            alpha[i] = __expf(m_i[i] - mn);
            m_i[i] = mn;
            const short p0 = f2bf(__expf(s0 - mn));
            const short p1 = f2bf(__expf(s1 - mn));
            const short p2 = f2bf(__expf(s2 - mn));
            const short p3 = f2bf(__expf(s3 - mn));
            pbuf[wave][quad * 4 + i][l16]      = p0;
            pbuf[wave][quad * 4 + i][l16 + 16] = p1;
            pbuf[wave][quad * 4 + i][l16 + 32] = p2;
            pbuf[wave][quad * 4 + i][l16 + 48] = p3;
            float rs = (bf2f(p0) + bf2f(p1)) + (bf2f(p2) + bf2f(p3));
#pragma unroll
            for (int off = 1; off < 16; off <<= 1)
                rs += __shfl_xor(rs, off);
            l_i[i] = l_i[i] * alpha[i] + rs;
        }

#pragma unroll
        for (int g = 0; g < 4; ++g)
#pragma unroll
            for (int i = 0; i < 4; ++i) O[g][i] *= alpha[i];

#pragma unroll
        for (int c = 0; c < 2; ++c) {
            const short8 ap = *(const short8*)(&pbuf[wave][l16][c * 32 + quad * 8]);
            const int kb = (c * 4 + quad) * 64;
            short8 bv8[4];
#pragma unroll
            for (int g = 0; g < 4; ++g)
                bv8[g] = *(const short8*)(Vc + (kb + g * 16 + l16) * 8);
            __builtin_amdgcn_s_setprio(1);
#pragma unroll
            for (int g = 0; g < 4; ++g)
                O[g] = __builtin_amdgcn_mfma_f32_16x16x32_bf16(ap, bv8[g], O[g], 0, 0, 0);
            __builtin_amdgcn_s_setprio(0);
        }
    }

#pragma unroll
    for (int i = 0; i < 4; ++i) {
        const int s = q0 + quad * 4 + i;
        if (s >= S_) continue;
        const float inv = 1.0f / l_i[i];
#pragma unroll
        for (int g = 0; g < 4; ++g)
            out[((size_t)b * S_ + s) * HID_ + h * HD_ + g * 16 + l16] = O[g][i] * inv;
    }
}

extern "C" void kernel_launch(void* const* d_in, const int* in_sizes, int n_in,
                              void* d_out, int out_size, void* d_ws, size_t ws_size,
                              hipStream_t stream) {
    (void)in_sizes; (void)n_in; (void)out_size; (void)ws_size;

    const float* X   = (const float*)d_in[0];
    const float* lat = (const float*)d_in[1];
    const float* Wq  = (const float*)d_in[2];
    const float* bq  = (const float*)d_in[3];
    const float* Wk  = (const float*)d_in[4];
    const float* bk  = (const float*)d_in[5];
    const float* Wv  = (const float*)d_in[6];
    const float* bv  = (const float*)d_in[7];
    const int* mixw  = (const int*)d_in[8];
    float* out = (float*)d_out;

    const size_t per = (size_t)B_ * NH_ * SPAD * HD_;   // 15,728,640
    short* qw   = (short*)d_ws;
    short* kw   = qw + per;
    short* vw   = kw + per;
    short* wimg = vw + per;                             // 18*12*8192 = 1,769,472
    short* ximg = wimg + (size_t)NT_ * KT_ * 8192;      // 160*12*8192 = 15,728,640

    convA_kernel<<<dim3(MT_, KT_), 256, 0, stream>>>(X, ximg);
    convB_kernel<<<dim3(NT_, KT_), 256, 0, stream>>>(Wq, Wk, Wv, wimg);
    gemm_kernel<<<dim3(NT_ * MT_), 256, 0, stream>>>(
        ximg, wimg, bq, bk, bv, lat, mixw, qw, kw, vw);
    attn_kernel<<<dim3(3840), 256, 0, stream>>>(qw, kw, vw, out);
}